// Round 1
// baseline (795.148 us; speedup 1.0000x reference)
//
#include <hip/hip_runtime.h>

typedef unsigned short u16;
typedef unsigned short ushort8 __attribute__((ext_vector_type(8)));
typedef unsigned short us4 __attribute__((ext_vector_type(4)));
typedef __bf16 bf16x8 __attribute__((ext_vector_type(8)));
typedef float f32x4 __attribute__((ext_vector_type(4)));

#define DEV static __device__ __forceinline__

// ---------- helpers ----------
DEV u16 f2bf(float f) {   // round-to-nearest-even f32 -> bf16 (values are tame, no NaN care)
    unsigned int u = __builtin_bit_cast(unsigned int, f);
    u += 0x7FFFu + ((u >> 16) & 1u);
    return (u16)(u >> 16);
}

DEV f32x4 mfma16(ushort8 a, ushort8 b, f32x4 c) {
    return __builtin_amdgcn_mfma_f32_16x16x32_bf16((bf16x8)a, (bf16x8)b, c, 0, 0, 0);
}

DEV void gload_lds16(const void* g, void* l) {   // async global->LDS, 16B/lane, dst = base + lane*16
    __builtin_amdgcn_global_load_lds(
        (const __attribute__((address_space(1))) void*)g,
        (__attribute__((address_space(3))) void*)l, 16, 0, 0);
}

// ---------- fp32 -> bf16 elementwise ----------
__global__ void cvt_kernel(const float* __restrict__ in, u16* __restrict__ out, int n) {
    int i = (blockIdx.x * 256 + threadIdx.x) * 4;
    if (i >= n) return;
    float4 f = *(const float4*)(in + i);
    us4 o;
    o.x = f2bf(f.x); o.y = f2bf(f.y); o.z = f2bf(f.z); o.w = f2bf(f.w);
    *(us4*)(out + i) = o;
}

// ---------- fp32 [R][C] -> bf16 [C][R] (tiled, coalesced both sides) ----------
__global__ void transpose_cvt(const float* __restrict__ in, u16* __restrict__ out, int R, int C) {
    __shared__ u16 tile[64][72];
    int c0 = blockIdx.x << 6, r0 = blockIdx.y << 6;
    int tx = threadIdx.x & 63, ty = threadIdx.x >> 6;
    for (int i = 0; i < 64; i += 4) {
        int r = i + ty;
        tile[r][tx] = f2bf(in[(size_t)(r0 + r) * C + c0 + tx]);
    }
    __syncthreads();
    for (int i = 0; i < 64; i += 4) {
        int r = i + ty;
        out[(size_t)(c0 + r) * R + r0 + tx] = tile[tx][r];
    }
}

// ---------- bf16 [bh][2048][512] -> bf16 [bh][512][2048] ----------
__global__ void transpose_bh(const u16* __restrict__ in, u16* __restrict__ out) {
    __shared__ u16 tile[64][72];
    int bh = blockIdx.z;
    int d0 = blockIdx.x << 6, t0 = blockIdx.y << 6;
    int tx = threadIdx.x & 63, ty = threadIdx.x >> 6;
    const u16* src = in + (size_t)bh * 2048 * 512;
    u16* dst = out + (size_t)bh * 512 * 2048;
    for (int i = 0; i < 64; i += 4) {
        int r = i + ty;
        tile[r][tx] = src[(size_t)(t0 + r) * 512 + d0 + tx];
    }
    __syncthreads();
    for (int i = 0; i < 64; i += 4) {
        int r = i + ty;
        dst[(size_t)(d0 + r) * 2048 + t0 + tx] = tile[tx][r];
    }
}

// ---------- GEMM: C[M][?] = A[M][Kc](bf16) @ Bt[N][Kc]^T(bf16) ----------
// MODE 0: bf16 store to [bh][t][512] layout (rows m=b*2048+t, cols n=h*512+d), *scale
// MODE 1: fp32 store to out[row*512+col] + bias[col]   (N == 512)
template <int MODE>
__launch_bounds__(256, 2)
__global__ void gemm_bt(const u16* __restrict__ A, const u16* __restrict__ Bt,
                        float scale, const float* __restrict__ bias,
                        void* __restrict__ out, int Kc) {
    __shared__ u16 Asub[128 * 32];
    __shared__ u16 Bsub[128 * 32];
    const int tid = threadIdx.x, lane = tid & 63, wv = tid >> 6;
    const int bm = blockIdx.y << 7, bn = blockIdx.x << 7;
    const int wr = (wv >> 1) << 6, wc = (wv & 1) << 6;
    const int lr = lane & 15, hi = lane >> 4;

    f32x4 acc[4][4] = {};

    // staging: wave w owns LDS bytes [w*2048, w*2048+2048), two 16B issues per lane
    int off0 = (wv * 2048 + lane * 16) >> 1;   // element offset in tile
    int row0 = off0 >> 5, k0e = off0 & 31;
    int off1 = off0 + 512;
    int row1 = off1 >> 5, k1e = off1 & 31;

    const u16* Ag0 = A + (size_t)(bm + row0) * Kc + k0e;
    const u16* Ag1 = A + (size_t)(bm + row1) * Kc + k1e;
    const u16* Bg0 = Bt + (size_t)(bn + row0) * Kc + k0e;
    const u16* Bg1 = Bt + (size_t)(bn + row1) * Kc + k1e;

    for (int kk = 0; kk < Kc; kk += 32) {
        __syncthreads();
        gload_lds16(Ag0 + kk, &Asub[wv * 1024]);
        gload_lds16(Ag1 + kk, &Asub[wv * 1024 + 512]);
        gload_lds16(Bg0 + kk, &Bsub[wv * 1024]);
        gload_lds16(Bg1 + kk, &Bsub[wv * 1024 + 512]);
        __syncthreads();

        ushort8 a[4], b[4];
#pragma unroll
        for (int m = 0; m < 4; ++m)
            a[m] = *(const ushort8*)&Asub[(wr + m * 16 + lr) * 32 + hi * 8];
#pragma unroll
        for (int n = 0; n < 4; ++n)
            b[n] = *(const ushort8*)&Bsub[(wc + n * 16 + lr) * 32 + hi * 8];
#pragma unroll
        for (int m = 0; m < 4; ++m)
#pragma unroll
            for (int n = 0; n < 4; ++n)
                acc[m][n] = mfma16(a[m], b[n], acc[m][n]);
    }

#pragma unroll
    for (int m = 0; m < 4; ++m)
#pragma unroll
        for (int n = 0; n < 4; ++n)
#pragma unroll
            for (int r = 0; r < 4; ++r) {
                int row = bm + wr + m * 16 + hi * 4 + r;   // C/D: row=(lane>>4)*4+reg
                int col = bn + wc + n * 16 + lr;           //      col=lane&15
                float v = acc[m][n][r] * scale;
                if constexpr (MODE == 0) {
                    size_t dst = ((size_t)((row >> 11) * 8 + (col >> 9)) * 2048 + (row & 2047)) * 512
                                 + (col & 511);
                    ((u16*)out)[dst] = f2bf(v);
                } else {
                    ((float*)out)[(size_t)row * 512 + col] = v + bias[col];
                }
            }
}

// ---------- flash attention ----------
// grid (32 qblocks, 16 bh), block 256 (4 waves). Q-block 64 rows; K-tile 32 keys.
// S-phase: wave owns 16 q rows (full D=512). PV: wave owns d-slice [wv*128, +128) of all 64 rows.
__launch_bounds__(256, 2)
__global__ void attn_kernel(const u16* __restrict__ Q, const u16* __restrict__ K,
                            const u16* __restrict__ Vt, u16* __restrict__ O) {
    __shared__ u16 Klds[32 * 512];      // XOR-swizzled rows of 1024B
    __shared__ u16 Vtlds[512 * 40];     // [d][32 keys + 8 pad]
    __shared__ u16 Plds[64 * 40];       // [q][32 keys + 8 pad]
    __shared__ float red[64];           // per-row alpha (per tile), then l (at end)

    const int tid = threadIdx.x, lane = tid & 63, wv = tid >> 6;
    const int lr = lane & 15, hi = lane >> 4;
    const int bh = blockIdx.y;
    const int q0 = blockIdx.x << 6;

    // Q fragments (A-layout: row=lane&15, k=(lane>>4)*8+j), pre-scaled by 512^-0.5 at projection
    ushort8 qf[16];
    {
        const char* Qg = (const char*)(Q + ((size_t)bh * 2048 + q0 + wv * 16 + lr) * 512) + hi * 16;
#pragma unroll
        for (int ks = 0; ks < 16; ++ks) qf[ks] = *(const ushort8*)(Qg + ks * 64);
    }

    f32x4 acc[4][8] = {};   // [q 16-block][d 16-frag within wave's 128-slice]
    float mrun[4], lrun[4];
#pragma unroll
    for (int r = 0; r < 4; ++r) { mrun[r] = -1e30f; lrun[r] = 0.f; }

    const char* Kg = (const char*)(K + (size_t)bh * 2048 * 512);
    const char* Vg = (const char*)(Vt + (size_t)bh * 512 * 2048);

    for (int kt = 0; kt < 2048; kt += 32) {
        __syncthreads();   // previous tile fully consumed
        // stage K tile [32][512] with row-XOR swizzle (rows are 1024B -> 32-way conflict otherwise)
#pragma unroll
        for (int j = 0; j < 8; ++j) {
            int idx = tid + j * 256;
            int r = idx >> 6, cb = (idx & 63) << 4;
            uint4 v = *(const uint4*)(Kg + (size_t)(kt + r) * 1024 + cb);
            *(uint4*)((char*)Klds + r * 1024 + (cb ^ ((r & 7) << 4))) = v;
        }
        // stage Vt tile [512][32] -> padded rows of 80B
#pragma unroll
        for (int j = 0; j < 8; ++j) {
            int idx = tid + j * 256;
            int d = idx >> 2, cb = (idx & 3) << 4;
            uint4 v = *(const uint4*)(Vg + (size_t)d * 4096 + kt * 2 + cb);
            *(uint4*)((char*)Vtlds + d * 80 + cb) = v;
        }
        __syncthreads();

        // S = Q K^T for wave's 16 rows x 32 keys
        f32x4 s0 = {}, s1 = {};
#pragma unroll
        for (int ks = 0; ks < 16; ++ks) {
            int swz = (ks * 64 + hi * 16) ^ ((lr & 7) << 4);
            ushort8 kf0 = *(const ushort8*)((const char*)Klds + lr * 1024 + swz);
            ushort8 kf1 = *(const ushort8*)((const char*)Klds + (lr + 16) * 1024 + swz);
            s0 = mfma16(qf[ks], kf0, s0);
            s1 = mfma16(qf[ks], kf1, s1);
        }

        // online softmax (row = wave-local q row wv*16 + hi*4 + r, col = lr)
        float alpha_r[4];
#pragma unroll
        for (int r = 0; r < 4; ++r) {
            float mx = fmaxf(s0[r], s1[r]);
            mx = fmaxf(mx, __shfl_xor(mx, 1));
            mx = fmaxf(mx, __shfl_xor(mx, 2));
            mx = fmaxf(mx, __shfl_xor(mx, 4));
            mx = fmaxf(mx, __shfl_xor(mx, 8));
            float mn = fmaxf(mrun[r], mx);
            float p0 = __expf(s0[r] - mn);
            float p1 = __expf(s1[r] - mn);
            float a = __expf(mrun[r] - mn);
            mrun[r] = mn;
            float ps = p0 + p1;
            ps += __shfl_xor(ps, 1);
            ps += __shfl_xor(ps, 2);
            ps += __shfl_xor(ps, 4);
            ps += __shfl_xor(ps, 8);
            lrun[r] = lrun[r] * a + ps;
            alpha_r[r] = a;
            int qr = wv * 16 + hi * 4 + r;
            Plds[qr * 40 + lr] = f2bf(p0);
            Plds[qr * 40 + 16 + lr] = f2bf(p1);
        }
        if (lr == 0) {
#pragma unroll
            for (int r = 0; r < 4; ++r) red[wv * 16 + hi * 4 + r] = alpha_r[r];
        }
        __syncthreads();   // P + alpha visible to all waves

        // rescale O by this tile's alpha, then PV over wave's d-slice
#pragma unroll
        for (int mf = 0; mf < 4; ++mf) {
            f32x4 a4 = *(const f32x4*)&red[mf * 16 + hi * 4];
#pragma unroll
            for (int nf = 0; nf < 8; ++nf)
#pragma unroll
                for (int r = 0; r < 4; ++r) acc[mf][nf][r] *= a4[r];
        }
        ushort8 pf[4];
#pragma unroll
        for (int mf = 0; mf < 4; ++mf)
            pf[mf] = *(const ushort8*)((const char*)Plds + (mf * 16 + lr) * 80 + hi * 16);
#pragma unroll
        for (int nf = 0; nf < 8; ++nf) {
            int vrow = wv * 128 + nf * 16 + lr;
            ushort8 vf = *(const ushort8*)((const char*)Vtlds + vrow * 80 + hi * 16);
#pragma unroll
            for (int mf = 0; mf < 4; ++mf) acc[mf][nf] = mfma16(pf[mf], vf, acc[mf][nf]);
        }
    }

    __syncthreads();                       // everyone done reading red (alpha)
    if (lr == 0) {
#pragma unroll
        for (int r = 0; r < 4; ++r) red[wv * 16 + hi * 4 + r] = lrun[r];
    }
    __syncthreads();

    const int b = bh >> 3, h = bh & 7;
#pragma unroll
    for (int mf = 0; mf < 4; ++mf) {
        f32x4 lv = *(const f32x4*)&red[mf * 16 + hi * 4];
#pragma unroll
        for (int nf = 0; nf < 8; ++nf) {
            int d = wv * 128 + nf * 16 + lr;
#pragma unroll
            for (int r = 0; r < 4; ++r) {
                int t = q0 + mf * 16 + hi * 4 + r;
                float v = acc[mf][nf][r] / lv[r];
                O[((size_t)(b * 2048 + t)) * 4096 + h * 512 + d] = f2bf(v);
            }
        }
    }
}

// ---------- host ----------
extern "C" void kernel_launch(void* const* d_in, const int* in_sizes, int n_in,
                              void* d_out, int out_size, void* d_ws, size_t ws_size,
                              hipStream_t stream) {
    const float* x  = (const float*)d_in[0];
    const float* Wq = (const float*)d_in[1];
    const float* Wk = (const float*)d_in[2];
    const float* Wv = (const float*)d_in[3];
    const float* Wu = (const float*)d_in[4];
    const float* bu = (const float*)d_in[5];

    char* ws = (char*)d_ws;
    const size_t MB = 1ull << 20;
    u16* xb  = (u16*)(ws + 0);          // 4 MB  x as bf16 [4096][512]
    u16* Wqt = (u16*)(ws + 4 * MB);     // 4 MB  Wq^T bf16 [4096][512]
    u16* Wkt = (u16*)(ws + 8 * MB);
    u16* Wvt = (u16*)(ws + 12 * MB);
    u16* Wut = (u16*)(ws + 16 * MB);    // 4 MB  Wu^T bf16 [512][4096]
    u16* Qb  = (u16*)(ws + 20 * MB);    // 32 MB [bh][t][d] (pre-scaled)
    u16* Kb  = (u16*)(ws + 52 * MB);    // 32 MB [bh][t][d]
    u16* Vb  = (u16*)(ws + 84 * MB);    // 32 MB [bh][t][d]
    u16* Vtb = (u16*)(ws + 116 * MB);   // 32 MB [bh][d][t]
    u16* Ob  = (u16*)(ws + 84 * MB);    // 32 MB [b*t][h*d]  (aliases Vb: V dead after transpose)

    cvt_kernel<<<2048, 256, 0, stream>>>(x, xb, 2 * 2048 * 512);
    transpose_cvt<<<dim3(64, 8), 256, 0, stream>>>(Wq, Wqt, 512, 4096);
    transpose_cvt<<<dim3(64, 8), 256, 0, stream>>>(Wk, Wkt, 512, 4096);
    transpose_cvt<<<dim3(64, 8), 256, 0, stream>>>(Wv, Wvt, 512, 4096);
    transpose_cvt<<<dim3(8, 64), 256, 0, stream>>>(Wu, Wut, 4096, 512);

    const float s2 = 0.04419417382415922f;   // 512^-0.5 == (k^-0.25)^2, folded into Q
    gemm_bt<0><<<dim3(32, 32), 256, 0, stream>>>(xb, Wqt, s2,   nullptr, Qb, 512);
    gemm_bt<0><<<dim3(32, 32), 256, 0, stream>>>(xb, Wkt, 1.0f, nullptr, Kb, 512);
    gemm_bt<0><<<dim3(32, 32), 256, 0, stream>>>(xb, Wvt, 1.0f, nullptr, Vb, 512);

    transpose_bh<<<dim3(8, 32, 16), 256, 0, stream>>>(Vb, Vtb);

    attn_kernel<<<dim3(32, 16), 256, 0, stream>>>(Qb, Kb, Vtb, Ob);

    gemm_bt<1><<<dim3(4, 32), 256, 0, stream>>>(Ob, Wut, 1.0f, bu, d_out, 4096);
}

// Round 2
// 606.527 us; speedup vs baseline: 1.3110x; 1.3110x over previous
//
#include <hip/hip_runtime.h>

typedef unsigned short u16;
typedef unsigned short ushort8 __attribute__((ext_vector_type(8)));
typedef unsigned short us4 __attribute__((ext_vector_type(4)));
typedef __bf16 bf16x8 __attribute__((ext_vector_type(8)));
typedef float f32x4 __attribute__((ext_vector_type(4)));

#define DEV static __device__ __forceinline__

// ---------- helpers ----------
DEV u16 f2bf(float f) {   // round-to-nearest-even f32 -> bf16
    unsigned int u = __builtin_bit_cast(unsigned int, f);
    u += 0x7FFFu + ((u >> 16) & 1u);
    return (u16)(u >> 16);
}

DEV f32x4 mfma16(ushort8 a, ushort8 b, f32x4 c) {
    return __builtin_amdgcn_mfma_f32_16x16x32_bf16((bf16x8)a, (bf16x8)b, c, 0, 0, 0);
}

DEV void gload_lds16(const void* g, void* l) {   // async global->LDS, dst = base + lane*16
    __builtin_amdgcn_global_load_lds(
        (const __attribute__((address_space(1))) void*)g,
        (__attribute__((address_space(3))) void*)l, 16, 0, 0);
}

// ---------- fp32 -> bf16 elementwise ----------
__global__ void cvt_kernel(const float* __restrict__ in, u16* __restrict__ out, int n) {
    int i = (blockIdx.x * 256 + threadIdx.x) * 4;
    if (i >= n) return;
    float4 f = *(const float4*)(in + i);
    us4 o;
    o.x = f2bf(f.x); o.y = f2bf(f.y); o.z = f2bf(f.z); o.w = f2bf(f.w);
    *(us4*)(out + i) = o;
}

// ---------- fp32 [R][C] -> bf16 [C][R] (tiled, coalesced both sides) ----------
__global__ void transpose_cvt(const float* __restrict__ in, u16* __restrict__ out, int R, int C) {
    __shared__ u16 tile[64][72];
    int c0 = blockIdx.x << 6, r0 = blockIdx.y << 6;
    int tx = threadIdx.x & 63, ty = threadIdx.x >> 6;
    for (int i = 0; i < 64; i += 4) {
        int r = i + ty;
        tile[r][tx] = f2bf(in[(size_t)(r0 + r) * C + c0 + tx]);
    }
    __syncthreads();
    for (int i = 0; i < 64; i += 4) {
        int r = i + ty;
        out[(size_t)(c0 + r) * R + r0 + tx] = tile[tx][r];
    }
}

// ---------- bf16 [bh][2048][512] -> bf16 [bh][512][2048] ----------
__global__ void transpose_bh(const u16* __restrict__ in, u16* __restrict__ out) {
    __shared__ u16 tile[64][72];
    int bh = blockIdx.z;
    int d0 = blockIdx.x << 6, t0 = blockIdx.y << 6;
    int tx = threadIdx.x & 63, ty = threadIdx.x >> 6;
    const u16* src = in + (size_t)bh * 2048 * 512;
    u16* dst = out + (size_t)bh * 512 * 2048;
    for (int i = 0; i < 64; i += 4) {
        int r = i + ty;
        tile[r][tx] = src[(size_t)(t0 + r) * 512 + d0 + tx];
    }
    __syncthreads();
    for (int i = 0; i < 64; i += 4) {
        int r = i + ty;
        dst[(size_t)(d0 + r) * 2048 + t0 + tx] = tile[tx][r];
    }
}

// ---------- GEMM: C[M][?] = A[M][Kc](bf16) @ Bt[N][Kc]^T(bf16) ----------
template <int MODE>
__launch_bounds__(256, 2)
__global__ void gemm_bt(const u16* __restrict__ A, const u16* __restrict__ Bt,
                        float scale, const float* __restrict__ bias,
                        void* __restrict__ out, int Kc) {
    __shared__ u16 Asub[128 * 32];
    __shared__ u16 Bsub[128 * 32];
    const int tid = threadIdx.x, lane = tid & 63, wv = tid >> 6;
    const int bm = blockIdx.y << 7, bn = blockIdx.x << 7;
    const int wr = (wv >> 1) << 6, wc = (wv & 1) << 6;
    const int lr = lane & 15, hi = lane >> 4;

    f32x4 acc[4][4] = {};

    int off0 = (wv * 2048 + lane * 16) >> 1;
    int row0 = off0 >> 5, k0e = off0 & 31;
    int off1 = off0 + 512;
    int row1 = off1 >> 5, k1e = off1 & 31;

    const u16* Ag0 = A + (size_t)(bm + row0) * Kc + k0e;
    const u16* Ag1 = A + (size_t)(bm + row1) * Kc + k1e;
    const u16* Bg0 = Bt + (size_t)(bn + row0) * Kc + k0e;
    const u16* Bg1 = Bt + (size_t)(bn + row1) * Kc + k1e;

    for (int kk = 0; kk < Kc; kk += 32) {
        __syncthreads();
        gload_lds16(Ag0 + kk, &Asub[wv * 1024]);
        gload_lds16(Ag1 + kk, &Asub[wv * 1024 + 512]);
        gload_lds16(Bg0 + kk, &Bsub[wv * 1024]);
        gload_lds16(Bg1 + kk, &Bsub[wv * 1024 + 512]);
        __syncthreads();

        ushort8 a[4], b[4];
#pragma unroll
        for (int m = 0; m < 4; ++m)
            a[m] = *(const ushort8*)&Asub[(wr + m * 16 + lr) * 32 + hi * 8];
#pragma unroll
        for (int n = 0; n < 4; ++n)
            b[n] = *(const ushort8*)&Bsub[(wc + n * 16 + lr) * 32 + hi * 8];
#pragma unroll
        for (int m = 0; m < 4; ++m)
#pragma unroll
            for (int n = 0; n < 4; ++n)
                acc[m][n] = mfma16(a[m], b[n], acc[m][n]);
    }

#pragma unroll
    for (int m = 0; m < 4; ++m)
#pragma unroll
        for (int n = 0; n < 4; ++n)
#pragma unroll
            for (int r = 0; r < 4; ++r) {
                int row = bm + wr + m * 16 + hi * 4 + r;
                int col = bn + wc + n * 16 + lr;
                float v = acc[m][n][r] * scale;
                if constexpr (MODE == 0) {
                    size_t dst = ((size_t)((row >> 11) * 8 + (col >> 9)) * 2048 + (row & 2047)) * 512
                                 + (col & 511);
                    ((u16*)out)[dst] = f2bf(v);
                } else {
                    ((float*)out)[(size_t)row * 512 + col] = v + bias[col];
                }
            }
}

// ---------- flash attention v2 ----------
// grid 512 blocks (XCD-chunked), block 256 (4 waves). QBLK=64, KVBLK=32.
// One barrier per KV tile: [prefetch K(t+1) via global_load_lds | S(t) | softmax | P,alpha -> LDS]
//   -> barrier -> [rescale (defer-max gated) | PV(t), V direct from global].
// K LDS double-buffered, XOR-swizzled via pre-swizzled global source (LDS linear).
// V never staged: d-split PV consumes each element once per block.
__launch_bounds__(256, 2)
__global__ void attn_kernel(const u16* __restrict__ Q, const u16* __restrict__ K,
                            const u16* __restrict__ Vt, u16* __restrict__ O) {
    __shared__ u16 Klds[2][32 * 512];            // 2 x 32KB
    __shared__ u16 Plds[2][64 * 40];             // [q][32 keys + 8 pad]
    __shared__ __align__(16) float red[2][64];   // per-row alpha
    __shared__ __align__(16) float lred[64];     // final l
    __shared__ int rflag[2][4];                  // per-wave "some row rescaled"

    const int tid = threadIdx.x, lane = tid & 63, wv = tid >> 6;
    const int lr = lane & 15, hi = lane >> 4;

    // XCD-chunked bijective swizzle: 512 blocks = 8 XCDs x 64; 2 bh per XCD chunk
    const int flat = blockIdx.x;
    const int nid = (flat & 7) * 64 + (flat >> 3);
    const int bh = nid >> 5;
    const int q0 = (nid & 31) << 6;

    // Q fragments in registers (A-layout: row=lane&15, k=(lane>>4)*8+j); Q pre-scaled by 512^-0.5
    ushort8 qf[16];
    {
        const char* Qg = (const char*)(Q + ((size_t)bh * 2048 + q0 + wv * 16 + lr) * 512) + hi * 16;
#pragma unroll
        for (int ks = 0; ks < 16; ++ks) qf[ks] = *(const ushort8*)(Qg + ks * 64);
    }

    f32x4 acc[4][8] = {};   // [q 16-block][d 16-frag within wave's 128-wide d-slice]
    float mrun[4], lrun[4];
#pragma unroll
    for (int r = 0; r < 4; ++r) { mrun[r] = -1e30f; lrun[r] = 0.f; }

    const char* Kg = (const char*)(K + (size_t)bh * 2048 * 512);
    const char* Vg = (const char*)(Vt + (size_t)bh * 512 * 2048);

    // prologue: stage tile 0 into buf 0 (wave wv stages rows [wv*8, wv*8+8))
#pragma unroll
    for (int r8 = 0; r8 < 8; ++r8) {
        int r = wv * 8 + r8;
        gload_lds16(Kg + (size_t)r * 1024 + ((lane ^ (r & 7)) << 4),
                    &Klds[0][(size_t)r * 512]);
    }
    __syncthreads();

    for (int t = 0; t < 64; ++t) {
        const int kt = t << 5;
        const int cb = t & 1;

        // prefetch next K tile into the other buffer (in flight across S+softmax)
        if (t + 1 < 64) {
            const char* Kgt = Kg + (size_t)(kt + 32) * 1024;
#pragma unroll
            for (int r8 = 0; r8 < 8; ++r8) {
                int r = wv * 8 + r8;
                gload_lds16(Kgt + (size_t)r * 1024 + ((lane ^ (r & 7)) << 4),
                            &Klds[cb ^ 1][(size_t)r * 512]);
            }
        }

        // S = Q K^T for this wave's 16 q-rows x 32 keys
        f32x4 s0 = {}, s1 = {};
        const char* Kb = (const char*)&Klds[cb][0];
#pragma unroll
        for (int ks = 0; ks < 16; ++ks) {
            int swz = (ks * 64 + hi * 16) ^ ((lr & 7) << 4);
            ushort8 kf0 = *(const ushort8*)(Kb + lr * 1024 + swz);
            ushort8 kf1 = *(const ushort8*)(Kb + (lr + 16) * 1024 + swz);
            s0 = mfma16(qf[ks], kf0, s0);
            s1 = mfma16(qf[ks], kf1, s1);
        }

        // online softmax with defer-max (THR=8): row = wv*16 + hi*4 + r, cols lr / lr+16
        bool upd = false;
#pragma unroll
        for (int r = 0; r < 4; ++r) {
            float mx = fmaxf(s0[r], s1[r]);
            mx = fmaxf(mx, __shfl_xor(mx, 1));
            mx = fmaxf(mx, __shfl_xor(mx, 2));
            mx = fmaxf(mx, __shfl_xor(mx, 4));
            mx = fmaxf(mx, __shfl_xor(mx, 8));
            float a = 1.0f;
            if (mx > mrun[r] + 8.0f) { a = __expf(mrun[r] - mx); mrun[r] = mx; upd = true; }
            float p0 = __expf(s0[r] - mrun[r]);
            float p1 = __expf(s1[r] - mrun[r]);
            float ps = p0 + p1;
            ps += __shfl_xor(ps, 1);
            ps += __shfl_xor(ps, 2);
            ps += __shfl_xor(ps, 4);
            ps += __shfl_xor(ps, 8);
            lrun[r] = lrun[r] * a + ps;
            int qr = wv * 16 + hi * 4 + r;
            Plds[cb][qr * 40 + lr] = f2bf(p0);
            Plds[cb][qr * 40 + 16 + lr] = f2bf(p1);
            if (lr == 0) red[cb][qr] = a;
        }
        if (lane == 0) rflag[cb][wv] = __any(upd) ? 1 : 0;

        __syncthreads();   // the ONE barrier: P/alpha visible; K(t+1) gload drained here too

        // rescale O only if some row's max moved (defer-max)
        if (rflag[cb][0] | rflag[cb][1] | rflag[cb][2] | rflag[cb][3]) {
#pragma unroll
            for (int mf = 0; mf < 4; ++mf) {
                f32x4 a4 = *(const f32x4*)&red[cb][mf * 16 + hi * 4];
#pragma unroll
                for (int nf = 0; nf < 8; ++nf)
#pragma unroll
                    for (int r = 0; r < 4; ++r) acc[mf][nf][r] *= a4[r];
            }
        }

        // PV: wave's d-slice [wv*128, +128) x all 64 q-rows; V direct from global (L2)
        ushort8 pf[4];
#pragma unroll
        for (int mf = 0; mf < 4; ++mf)
            pf[mf] = *(const ushort8*)((const char*)&Plds[cb][0] + (mf * 16 + lr) * 80 + hi * 16);
#pragma unroll
        for (int nf = 0; nf < 8; ++nf) {
            int d = wv * 128 + nf * 16 + lr;
            ushort8 vf = *(const ushort8*)(Vg + (size_t)d * 4096 + (size_t)kt * 2 + hi * 16);
#pragma unroll
            for (int mf = 0; mf < 4; ++mf) acc[mf][nf] = mfma16(pf[mf], vf, acc[mf][nf]);
        }
    }

    // final l for all 64 rows -> LDS
    if (lr == 0) {
#pragma unroll
        for (int r = 0; r < 4; ++r) lred[wv * 16 + hi * 4 + r] = lrun[r];
    }
    __syncthreads();

    const int b = bh >> 3, h = bh & 7;
#pragma unroll
    for (int mf = 0; mf < 4; ++mf) {
        f32x4 lv = *(const f32x4*)&lred[mf * 16 + hi * 4];
        f32x4 inv;
#pragma unroll
        for (int r = 0; r < 4; ++r) inv[r] = 1.0f / lv[r];
#pragma unroll
        for (int nf = 0; nf < 8; ++nf) {
            int d = wv * 128 + nf * 16 + lr;
#pragma unroll
            for (int r = 0; r < 4; ++r) {
                int t = q0 + mf * 16 + hi * 4 + r;
                O[((size_t)(b * 2048 + t)) * 4096 + h * 512 + d] = f2bf(acc[mf][nf][r] * inv[r]);
            }
        }
    }
}

// ---------- host ----------
extern "C" void kernel_launch(void* const* d_in, const int* in_sizes, int n_in,
                              void* d_out, int out_size, void* d_ws, size_t ws_size,
                              hipStream_t stream) {
    const float* x  = (const float*)d_in[0];
    const float* Wq = (const float*)d_in[1];
    const float* Wk = (const float*)d_in[2];
    const float* Wv = (const float*)d_in[3];
    const float* Wu = (const float*)d_in[4];
    const float* bu = (const float*)d_in[5];

    char* ws = (char*)d_ws;
    const size_t MB = 1ull << 20;
    u16* xb  = (u16*)(ws + 0);          // 4 MB  x as bf16 [4096][512]
    u16* Wqt = (u16*)(ws + 4 * MB);     // 4 MB  Wq^T bf16 [4096][512]
    u16* Wkt = (u16*)(ws + 8 * MB);
    u16* Wvt = (u16*)(ws + 12 * MB);
    u16* Wut = (u16*)(ws + 16 * MB);    // 4 MB  Wu^T bf16 [512][4096]
    u16* Qb  = (u16*)(ws + 20 * MB);    // 32 MB [bh][t][d] (pre-scaled)
    u16* Kb  = (u16*)(ws + 52 * MB);    // 32 MB [bh][t][d]
    u16* Vb  = (u16*)(ws + 84 * MB);    // 32 MB [bh][t][d]
    u16* Vtb = (u16*)(ws + 116 * MB);   // 32 MB [bh][d][t]
    u16* Ob  = (u16*)(ws + 84 * MB);    // 32 MB [b*t][h*d]  (aliases Vb: V dead after transpose)

    cvt_kernel<<<2048, 256, 0, stream>>>(x, xb, 2 * 2048 * 512);
    transpose_cvt<<<dim3(64, 8), 256, 0, stream>>>(Wq, Wqt, 512, 4096);
    transpose_cvt<<<dim3(64, 8), 256, 0, stream>>>(Wk, Wkt, 512, 4096);
    transpose_cvt<<<dim3(64, 8), 256, 0, stream>>>(Wv, Wvt, 512, 4096);
    transpose_cvt<<<dim3(8, 64), 256, 0, stream>>>(Wu, Wut, 4096, 512);

    const float s2 = 0.04419417382415922f;   // 512^-0.5 == (k^-0.25)^2, folded into Q
    gemm_bt<0><<<dim3(32, 32), 256, 0, stream>>>(xb, Wqt, s2,   nullptr, Qb, 512);
    gemm_bt<0><<<dim3(32, 32), 256, 0, stream>>>(xb, Wkt, 1.0f, nullptr, Kb, 512);
    gemm_bt<0><<<dim3(32, 32), 256, 0, stream>>>(xb, Wvt, 1.0f, nullptr, Vb, 512);

    transpose_bh<<<dim3(8, 32, 16), 256, 0, stream>>>(Vb, Vtb);

    attn_kernel<<<512, 256, 0, stream>>>(Qb, Kb, Vtb, Ob);

    gemm_bt<1><<<dim3(4, 32), 256, 0, stream>>>(Ob, Wut, 1.0f, bu, d_out, 4096);
}